// Round 1
// baseline (1308.922 us; speedup 1.0000x reference)
//
#include <hip/hip_runtime.h>
#include <cstdint>
#include <cstddef>

#define LN_EPS 1e-5f

typedef __attribute__((ext_vector_type(8))) short short8;   // 8 bf16 = 4 VGPRs
typedef __attribute__((ext_vector_type(4))) float f32x4;    // MFMA accumulator

static __device__ __forceinline__ unsigned short f2bf(float x) {
    union { float f; unsigned u; } v; v.f = x;
    unsigned r = v.u + 0x7FFFu + ((v.u >> 16) & 1u);   // round-to-nearest-even
    return (unsigned short)(r >> 16);
}
static __device__ __forceinline__ float bf2f(unsigned short b) {
    union { unsigned u; float f; } v; v.u = ((unsigned)b) << 16;
    return v.f;
}

// ---------------- weight prep: fp32 -> bf16, fold zero_time_feat into q-bias ----
__global__ void prep_kernel(const float* __restrict__ Wq, const float* __restrict__ bq,
                            const float* __restrict__ Wk, const float* __restrict__ Wv,
                            const float* __restrict__ Wout, const float* __restrict__ tb,
                            unsigned short* __restrict__ wkv, unsigned short* __restrict__ wq,
                            unsigned short* __restrict__ wout, float* __restrict__ qbias) {
    int tid = blockIdx.x * blockDim.x + threadIdx.x;
    if (tid < 256 * 384) {           // WKV: rows 0..127 = Wk, 128..255 = Wv  [256][384]
        int o = tid / 384, k = tid % 384;
        float w = (o < 128) ? Wk[o * 384 + k] : Wv[(o - 128) * 384 + k];
        wkv[tid] = f2bf(w);
    }
    if (tid < 128 * 128) {           // Wq first 128 input cols  [128][128]
        int o = tid / 128, i = tid % 128;
        wq[tid] = f2bf(Wq[o * 256 + i]);
    }
    if (tid < 128 * 256) {           // Wout  [128][256]
        wout[tid] = f2bf(Wout[tid]);
    }
    if (tid < 128) {                 // qbias[o] = bq[o] + sum_t cos(tb[t]) * Wq[o][128+t]
        float s = bq[tid];
        for (int t = 0; t < 128; ++t) s += cosf(tb[t]) * Wq[tid * 256 + 128 + t];
        qbias[tid] = s;
    }
}

// ---------------- fused K/V GEMM: [h_src | f | cos(dt*freq+tb)] @ WKV^T -------
// block = 256 thr (4 waves), tile 64 edges x 256 outputs, K=384 in 12 steps of 32
__launch_bounds__(256)
__global__ void gemm_kv_kernel(const float* __restrict__ h, const float* __restrict__ f,
                               const float* __restrict__ dt, const float* __restrict__ freq,
                               const float* __restrict__ tb,
                               const unsigned short* __restrict__ wkv,
                               const float* __restrict__ bk, const float* __restrict__ bv,
                               unsigned short* __restrict__ Kb, unsigned short* __restrict__ Vb,
                               int Nd, int E) {
    // A staged directly in MFMA fragment order: [mt(4)][ks(12)][lane(64)][8 bf16]
    __shared__ unsigned short ldsA[4 * 12 * 64 * 8];
    const int tid = threadIdx.x;
    const long e_base = (long)blockIdx.x * 64;

    for (int g = tid; g < 64 * 96; g += 256) {          // 64 rows x 96 float4-groups
        int r  = g / 96;
        int c4 = (g % 96) * 4;
        long e = e_base + r; if (e >= E) e = E - 1;
        float v0, v1, v2, v3;
        if (c4 < 128) {
            float4 x = *(const float4*)(h + ((long)Nd + e) * 128 + c4);
            v0 = x.x; v1 = x.y; v2 = x.z; v3 = x.w;
        } else if (c4 < 256) {
            float4 x = *(const float4*)(f + e * 128 + (c4 - 128));
            v0 = x.x; v1 = x.y; v2 = x.z; v3 = x.w;
        } else {
            int t = c4 - 256;
            float d = dt[e];
            v0 = __cosf(fmaf(d, freq[t + 0], tb[t + 0]));
            v1 = __cosf(fmaf(d, freq[t + 1], tb[t + 1]));
            v2 = __cosf(fmaf(d, freq[t + 2], tb[t + 2]));
            v3 = __cosf(fmaf(d, freq[t + 3], tb[t + 3]));
        }
        int mt   = r >> 4;
        int lane = (r & 15) | (((c4 >> 3) & 3) << 4);
        int ks   = c4 >> 5;
        int base = ((mt * 12 + ks) * 64 + lane) * 8 + (c4 & 7);
        *(unsigned*)&ldsA[base]     = (unsigned)f2bf(v0) | ((unsigned)f2bf(v1) << 16);
        *(unsigned*)&ldsA[base + 2] = (unsigned)f2bf(v2) | ((unsigned)f2bf(v3) << 16);
    }
    __syncthreads();

    const int w = tid >> 6, l = tid & 63, ln = l & 15, lq = l >> 4;
    f32x4 acc[4][4] = {};
    for (int ks = 0; ks < 12; ++ks) {
        short8 bfr[4], afr[4];
        #pragma unroll
        for (int nt = 0; nt < 4; ++nt) {
            int row = w * 64 + nt * 16 + ln;             // W stored [N][K] row-major
            bfr[nt] = *(const short8*)(wkv + row * 384 + ks * 32 + lq * 8);
        }
        #pragma unroll
        for (int mt = 0; mt < 4; ++mt)
            afr[mt] = *(const short8*)&ldsA[((mt * 12 + ks) * 64 + l) * 8];
        #pragma unroll
        for (int mt = 0; mt < 4; ++mt)
            #pragma unroll
            for (int nt = 0; nt < 4; ++nt)
                acc[mt][nt] = __builtin_amdgcn_mfma_f32_16x16x32_bf16(
                    afr[mt], bfr[nt], acc[mt][nt], 0, 0, 0);
    }
    #pragma unroll
    for (int mt = 0; mt < 4; ++mt) {
        #pragma unroll
        for (int nt = 0; nt < 4; ++nt) {
            int cg = w * 64 + nt * 16 + ln;              // wave-uniform K/V split (w<2 -> K)
            float bias = (cg < 128) ? bk[cg] : bv[cg - 128];
            #pragma unroll
            for (int rg = 0; rg < 4; ++rg) {
                long e = e_base + mt * 16 + lq * 4 + rg;
                if (e >= E) continue;
                unsigned short ob = f2bf(acc[mt][nt][rg] + bias);
                if (cg < 128) Kb[e * 128 + cg]         = ob;
                else          Vb[e * 128 + (cg - 128)] = ob;
            }
        }
    }
}

// ---------------- node GEMM: out[M][128] = [src0 | src1] @ W^T + bias (opt relu) ---
// ksteps = Kd/32 (4 for Q, 8 for Wout). block 256 thr, tile 64 rows x 128 cols.
__launch_bounds__(256)
__global__ void gemm_node_kernel(const float* __restrict__ src0, const float* __restrict__ src1,
                                 const unsigned short* __restrict__ W, const float* __restrict__ bias,
                                 float* __restrict__ out, int M, int ksteps, int do_relu) {
    __shared__ unsigned short ldsA[4 * 8 * 64 * 8];      // up to Kd=256
    const int tid = threadIdx.x;
    const long m_base = (long)blockIdx.x * 64;
    const int Kd = ksteps * 32;
    const int g4 = Kd / 4;

    for (int g = tid; g < 64 * g4; g += 256) {
        int r  = g / g4;
        int c4 = (g % g4) * 4;
        long m = m_base + r; if (m >= M) m = M - 1;
        float4 x = (c4 < 128) ? *(const float4*)(src0 + m * 128 + c4)
                              : *(const float4*)(src1 + m * 128 + (c4 - 128));
        int lane = (r & 15) | (((c4 >> 3) & 3) << 4);
        int base = (((r >> 4) * ksteps + (c4 >> 5)) * 64 + lane) * 8 + (c4 & 7);
        *(unsigned*)&ldsA[base]     = (unsigned)f2bf(x.x) | ((unsigned)f2bf(x.y) << 16);
        *(unsigned*)&ldsA[base + 2] = (unsigned)f2bf(x.z) | ((unsigned)f2bf(x.w) << 16);
    }
    __syncthreads();

    const int w = tid >> 6, l = tid & 63, ln = l & 15, lq = l >> 4;
    f32x4 acc[4][2] = {};
    for (int ks = 0; ks < ksteps; ++ks) {
        short8 bfr[2], afr[4];
        #pragma unroll
        for (int nt = 0; nt < 2; ++nt) {
            int row = w * 32 + nt * 16 + ln;
            bfr[nt] = *(const short8*)(W + row * Kd + ks * 32 + lq * 8);
        }
        #pragma unroll
        for (int mt = 0; mt < 4; ++mt)
            afr[mt] = *(const short8*)&ldsA[((mt * ksteps + ks) * 64 + l) * 8];
        #pragma unroll
        for (int mt = 0; mt < 4; ++mt)
            #pragma unroll
            for (int nt = 0; nt < 2; ++nt)
                acc[mt][nt] = __builtin_amdgcn_mfma_f32_16x16x32_bf16(
                    afr[mt], bfr[nt], acc[mt][nt], 0, 0, 0);
    }
    #pragma unroll
    for (int mt = 0; mt < 4; ++mt) {
        #pragma unroll
        for (int nt = 0; nt < 2; ++nt) {
            int cg = w * 32 + nt * 16 + ln;
            float b = bias[cg];
            #pragma unroll
            for (int rg = 0; rg < 4; ++rg) {
                long m = m_base + mt * 16 + lq * 4 + rg;
                if (m >= M) continue;
                float val = acc[mt][nt][rg] + b;
                if (do_relu) val = fmaxf(val, 0.f);
                out[m * 128 + cg] = val;
            }
        }
    }
}

// ---------------- counting sort of edges by dst ----------------
__global__ void hist_kernel(const int* __restrict__ dst, int* __restrict__ counts, int E) {
    int e = blockIdx.x * blockDim.x + threadIdx.x;
    if (e < E) atomicAdd(&counts[dst[e]], 1);
}

__global__ void scan_kernel(const int* __restrict__ counts, int* __restrict__ offsets,
                            int* __restrict__ cursor, int Nd) {
    __shared__ int sdata[1024];
    int t = threadIdx.x;
    int C = (Nd + 1023) / 1024;
    int b0 = t * C;
    int s = 0;
    for (int i = 0; i < C; ++i) { int idx = b0 + i; if (idx < Nd) s += counts[idx]; }
    sdata[t] = s;
    __syncthreads();
    for (int off = 1; off < 1024; off <<= 1) {
        int v = (t >= off) ? sdata[t - off] : 0;
        __syncthreads();
        sdata[t] += v;
        __syncthreads();
    }
    int run = sdata[t] - s;                              // exclusive prefix of this chunk
    for (int i = 0; i < C; ++i) {
        int idx = b0 + i;
        if (idx < Nd) { offsets[idx] = run; cursor[idx] = run; run += counts[idx]; }
    }
}

__global__ void scatter_kernel(const int* __restrict__ dst, int* __restrict__ cursor,
                               int* __restrict__ order, int E) {
    int e = blockIdx.x * blockDim.x + threadIdx.x;
    if (e < E) { int pos = atomicAdd(&cursor[dst[e]], 1); order[pos] = e; }
}

// ---------------- attention: one block per dst node, online softmax ----------------
__launch_bounds__(128)
__global__ void attn_kernel(const float* __restrict__ Q, const unsigned short* __restrict__ Kb,
                            const unsigned short* __restrict__ Vb,
                            const int* __restrict__ order, const int* __restrict__ offsets,
                            const int* __restrict__ counts, float* __restrict__ agg) {
    const int d = blockIdx.x;
    const int t = threadIdx.x;                           // channel; head = t>>4
    const int beg = offsets[d];
    const int n   = counts[d];
    const float q = Q[(long)d * 128 + t];

    float m = -3.0e38f, lsum = 0.f, acc = 0.f;
    float kk = 0.f, vv = 0.f;
    if (n > 0) {
        int e0 = order[beg];
        kk = bf2f(Kb[(long)e0 * 128 + t]);
        vv = bf2f(Vb[(long)e0 * 128 + t]);
    }
    for (int i = 0; i < n; ++i) {
        float ck = kk, cv = vv;
        if (i + 1 < n) {                                 // prefetch next edge's rows
            int e2 = order[beg + i + 1];
            kk = bf2f(Kb[(long)e2 * 128 + t]);
            vv = bf2f(Vb[(long)e2 * 128 + t]);
        }
        float p = q * ck;
        p += __shfl_xor(p, 1, 16);
        p += __shfl_xor(p, 2, 16);
        p += __shfl_xor(p, 4, 16);
        p += __shfl_xor(p, 8, 16);                       // per-head dot (16 chan)
        float logit = (p > 0.f) ? p : 0.2f * p;          // leaky_relu 0.2
        float mn = fmaxf(m, logit);
        float sc = __expf(m - mn);
        float pe = __expf(logit - mn);
        lsum = lsum * sc + pe;
        acc  = acc * sc + pe * cv;
        m = mn;
    }
    agg[(long)d * 128 + t] = (n > 0) ? acc / lsum : 0.f;
}

// ---------------- layernorm (one wave per row) ----------------
__launch_bounds__(256)
__global__ void ln_kernel(const float* __restrict__ rst, const float* __restrict__ gamma,
                          const float* __restrict__ beta, float* __restrict__ out, int Nd) {
    int wave = threadIdx.x >> 6;
    int lane = threadIdx.x & 63;
    long row = (long)blockIdx.x * 4 + wave;
    if (row >= Nd) return;
    float x0 = rst[row * 128 + lane];
    float x1 = rst[row * 128 + 64 + lane];
    float s = x0 + x1, sq = x0 * x0 + x1 * x1;
    #pragma unroll
    for (int off = 32; off >= 1; off >>= 1) {
        s  += __shfl_xor(s, off, 64);
        sq += __shfl_xor(sq, off, 64);
    }
    float mean = s * (1.f / 128.f);
    float var  = sq * (1.f / 128.f) - mean * mean;
    float rstd = rsqrtf(var + LN_EPS);
    out[row * 128 + lane]      = (x0 - mean) * rstd * gamma[lane]      + beta[lane];
    out[row * 128 + 64 + lane] = (x1 - mean) * rstd * gamma[lane + 64] + beta[lane + 64];
}

// ---------------- host ----------------
extern "C" void kernel_launch(void* const* d_in, const int* in_sizes, int n_in,
                              void* d_out, int out_size, void* d_ws, size_t ws_size,
                              hipStream_t stream) {
    const float* h    = (const float*)d_in[0];
    const float* f    = (const float*)d_in[1];
    const float* dt   = (const float*)d_in[2];
    const int*   dst  = (const int*)d_in[3];
    const float* freq = (const float*)d_in[4];
    const float* tb   = (const float*)d_in[5];
    const float* Wq   = (const float*)d_in[6];
    const float* bq   = (const float*)d_in[7];
    const float* Wk   = (const float*)d_in[8];
    const float* bk   = (const float*)d_in[9];
    const float* Wv   = (const float*)d_in[10];
    const float* bv   = (const float*)d_in[11];
    const float* Wout = (const float*)d_in[12];
    const float* bout = (const float*)d_in[13];
    const float* gamma= (const float*)d_in[14];
    const float* beta = (const float*)d_in[15];

    const int E  = in_sizes[2];
    const int Nd = in_sizes[0] / 128 - E;

    char* ws = (char*)d_ws;
    size_t off = 0;
    auto alloc = [&](size_t b) {
        off = (off + 255) & ~(size_t)255;
        char* p = ws + off; off += b; return p;
    };
    unsigned short* wkv   = (unsigned short*)alloc(256 * 384 * 2);
    unsigned short* wq    = (unsigned short*)alloc(128 * 128 * 2);
    unsigned short* wout  = (unsigned short*)alloc(128 * 256 * 2);
    float*          qbias = (float*)alloc(128 * 4);
    float*          Q     = (float*)alloc((size_t)Nd * 128 * 4);
    unsigned short* Kb    = (unsigned short*)alloc((size_t)E * 128 * 2);
    unsigned short* Vb    = (unsigned short*)alloc((size_t)E * 128 * 2);
    float*          agg   = (float*)alloc((size_t)Nd * 128 * 4);
    int*            counts= (int*)alloc((size_t)Nd * 4);
    int*            offs  = (int*)alloc((size_t)Nd * 4);
    int*            cursor= (int*)alloc((size_t)Nd * 4);
    int*            order = (int*)alloc((size_t)E * 4);
    float*          rst   = (float*)Kb;   // alias: Kb dead after attention

    hipMemsetAsync(counts, 0, (size_t)Nd * 4, stream);
    prep_kernel<<<(256 * 384 + 255) / 256, 256, 0, stream>>>(Wq, bq, Wk, Wv, Wout, tb,
                                                             wkv, wq, wout, qbias);
    hist_kernel<<<(E + 255) / 256, 256, 0, stream>>>(dst, counts, E);
    scan_kernel<<<1, 1024, 0, stream>>>(counts, offs, cursor, Nd);
    scatter_kernel<<<(E + 255) / 256, 256, 0, stream>>>(dst, cursor, order, E);
    gemm_node_kernel<<<(Nd + 63) / 64, 256, 0, stream>>>(h, nullptr, wq, qbias, Q, Nd, 4, 0);
    gemm_kv_kernel<<<(E + 63) / 64, 256, 0, stream>>>(h, f, dt, freq, tb, wkv, bk, bv,
                                                      Kb, Vb, Nd, E);
    attn_kernel<<<Nd, 128, 0, stream>>>(Q, Kb, Vb, order, offs, counts, agg);
    gemm_node_kernel<<<(Nd + 63) / 64, 256, 0, stream>>>(agg, h, wout, bout, rst, Nd, 8, 1);
    ln_kernel<<<(Nd + 3) / 4, 256, 0, stream>>>(rst, gamma, beta, (float*)d_out, Nd);
}